// Round 1
// baseline (10765.900 us; speedup 1.0000x reference)
//
#include <hip/hip_runtime.h>
#include <math.h>

#define B_ 2048
#define T_ 512
#define D_ 8
#define H_ 64
#define L_ 16
#define P_ 2

// ---- workspace layout (float offsets) ----
#define OFF_AE_IH   0                       // [k=8][j=64][g=4]   = 2048
#define OFF_AE_HH   2048                    // [k=64][j=64][g=4]  = 16384
#define OFF_AD      18432                   // ih [64][64][4] + hh [64][64][4] = 32768
#define OFF_WOUT    51200                   // [i=8][d=8][c=8]    = 512
#define OFF_INP0    51712                   // 64
#define OFF_BE      51776                   // 256
#define OFF_BD      52032                   // 256
#define OFF_H0      52288                   // B*H
#define OFF_C0      (OFF_H0 + B_*H_)
#define WS_FLOATS   (OFF_C0 + B_*H_)

__device__ __forceinline__ float sigm(float x) { return 1.0f / (1.0f + __expf(-x)); }
__device__ __forceinline__ float tanhf_(float x) {
  float ax = fabsf(x);
  float e  = __expf(-2.0f * ax);
  float r  = (1.0f - e) / (1.0f + e);
  return copysignf(r, x);
}
__device__ __forceinline__ float lrelu(float x) { return x >= 0.0f ? x : 0.01f * x; }
__device__ __forceinline__ float rdlane(float v, int l) {
  return __int_as_float(__builtin_amdgcn_readlane(__float_as_int(v), l));
}
__device__ __forceinline__ float wsum(float v) {
#pragma unroll
  for (int off = 32; off > 0; off >>= 1) v += __shfl_xor(v, off, 64);
  return v;
}

// ---------------- prep: repack weights / combine biases / start embedding ----------------
struct PrepP {
  const float* W_ih_e; const float* W_hh_e; const float* b_ih_e; const float* b_hh_e;
  const float* W_ih_d; const float* W_hh_d; const float* b_ih_d; const float* b_hh_d;
  const float* W_out;  const float* start;  const float* W_emb;  const float* b_emb;
  float* ws;
};

__global__ __launch_bounds__(256) void prep_kernel(PrepP p) {
  int idx = blockIdx.x * 256 + threadIdx.x;
  if (idx < 2048) {                                    // Ae_ih [k][j][g]
    int k = idx >> 8, j = (idx >> 2) & 63, g = idx & 3;
    p.ws[OFF_AE_IH + idx] = p.W_ih_e[(g * 64 + j) * 8 + k];
  } else if (idx < 2048 + 16384) {                     // Ae_hh
    int i2 = idx - 2048;
    int k = i2 >> 8, j = (i2 >> 2) & 63, g = i2 & 3;
    p.ws[OFF_AE_HH + i2] = p.W_hh_e[(g * 64 + j) * 64 + k];
  } else if (idx < 2048 + 2 * 16384) {                 // Ad_ih
    int i2 = idx - (2048 + 16384);
    int k = i2 >> 8, j = (i2 >> 2) & 63, g = i2 & 3;
    p.ws[OFF_AD + i2] = p.W_ih_d[(g * 64 + j) * 64 + k];
  } else if (idx < 2048 + 3 * 16384) {                 // Ad_hh
    int i2 = idx - (2048 + 2 * 16384);
    int k = i2 >> 8, j = (i2 >> 2) & 63, g = i2 & 3;
    p.ws[OFF_AD + 16384 + i2] = p.W_hh_d[(g * 64 + j) * 64 + k];
  } else if (idx < OFF_WOUT + 512) {                   // W_out_s[i][d][c] = W_out[d][c*8+i]
    int i2 = idx - OFF_WOUT;
    int i = i2 >> 6, d = (i2 >> 3) & 7, c = i2 & 7;
    p.ws[OFF_WOUT + i2] = p.W_out[d * 64 + c * 8 + i];
  } else if (idx < OFF_INP0 + 64) {                    // inp0 = start @ W_emb^T + b_emb
    int j = idx - OFF_INP0;
    float s = p.b_emb[j];
#pragma unroll
    for (int d = 0; d < 8; ++d) s += p.start[d] * p.W_emb[j * 8 + d];
    p.ws[OFF_INP0 + j] = s;
  } else if (idx < OFF_BE + 256) {
    int r = idx - OFF_BE;
    p.ws[OFF_BE + r] = p.b_ih_e[r] + p.b_hh_e[r];
  } else if (idx < OFF_BD + 256) {
    int r = idx - OFF_BD;
    p.ws[OFF_BD + r] = p.b_ih_d[r] + p.b_hh_d[r];
  }
}

// ---------------- encoder: 512-step LSTM + mu/logvar + heads + decoder init ----------------
struct EncP {
  const float* x; const float* ws;
  const float* W_mu; const float* b_mu; const float* W_lv; const float* b_lv;
  const float* W_l2h; const float* b_l2h; const float* W_l2h2; const float* b_l2h2;
  const float* W_seq; const float* b_seq; const float* W_seq2; const float* b_seq2;
  const float* W_m1; const float* b_m1; const float* W_m2; const float* b_m2;
  const float* W_m3; const float* b_m3;
  float* out_mu; float* out_lv; float* out_num; float* out_mass;
  float* ws_h0; float* ws_c0;
};

__global__ __launch_bounds__(256) void enc_kernel(EncP p) {
  __shared__ float sAih[8 * 64 * 4];      // [k][j][g]
  __shared__ float sAhh[64 * 64 * 4];     // [k][j][g]
  __shared__ float sX[8 * 32 * 8];        // [seg][tt][d]
  int tid = threadIdx.x;
  {
    const float4* s1 = (const float4*)(p.ws + OFF_AE_IH);
    float4* d1 = (float4*)sAih;
    for (int i = tid; i < 512; i += 256) d1[i] = s1[i];
    const float4* s2 = (const float4*)(p.ws + OFF_AE_HH);
    float4* d2 = (float4*)sAhh;
    for (int i = tid; i < 4096; i += 256) d2[i] = s2[i];
  }
  __syncthreads();

  int wave = tid >> 6, lane = tid & 63;
  int b0 = blockIdx.x * 8 + wave * 2;          // this wave owns batches b0, b0+1
  const int w2 = wave * 2;

  float be0 = p.ws[OFF_BE + lane],       be1 = p.ws[OFF_BE + 64 + lane],
        be2 = p.ws[OFF_BE + 128 + lane], be3 = p.ws[OFF_BE + 192 + lane];

  float h_a = 0.f, h_b = 0.f, c_a = 0.f, c_b = 0.f;

  for (int tc = 0; tc < 16; ++tc) {
    // wave-private x staging: this wave's lanes load exactly its own 2 batches
    {
      int bs = lane >> 5, pos = lane & 31;
      const float* s = p.x + ((size_t)(b0 + bs) * T_ + tc * 32) * 8 + pos * 8;
      float4 v0 = *(const float4*)s;
      float4 v1 = *(const float4*)(s + 4);
      float* d = &sX[(w2 + bs) * 256 + pos * 8];
      *(float4*)d = v0;
      *(float4*)(d + 4) = v1;
    }
    for (int tt = 0; tt < 32; ++tt) {
      float4 xa0 = *(const float4*)&sX[w2 * 256 + tt * 8];
      float4 xa1 = *(const float4*)&sX[w2 * 256 + tt * 8 + 4];
      float4 xb0 = *(const float4*)&sX[(w2 + 1) * 256 + tt * 8];
      float4 xb1 = *(const float4*)&sX[(w2 + 1) * 256 + tt * 8 + 4];
      float xav[8] = {xa0.x, xa0.y, xa0.z, xa0.w, xa1.x, xa1.y, xa1.z, xa1.w};
      float xbv[8] = {xb0.x, xb0.y, xb0.z, xb0.w, xb1.x, xb1.y, xb1.z, xb1.w};

      float aia = be0, afa = be1, aga = be2, aoa = be3;
      float aib = be0, afb = be1, agb = be2, aob = be3;
#pragma unroll
      for (int k = 0; k < 8; ++k) {
        float4 w = *(const float4*)&sAih[(k * 64 + lane) * 4];
        aia = fmaf(w.x, xav[k], aia); afa = fmaf(w.y, xav[k], afa);
        aga = fmaf(w.z, xav[k], aga); aoa = fmaf(w.w, xav[k], aoa);
        aib = fmaf(w.x, xbv[k], aib); afb = fmaf(w.y, xbv[k], afb);
        agb = fmaf(w.z, xbv[k], agb); aob = fmaf(w.w, xbv[k], aob);
      }
#pragma unroll
      for (int k = 0; k < 64; ++k) {
        float4 w = *(const float4*)&sAhh[(k * 64 + lane) * 4];
        float ha = rdlane(h_a, k), hb = rdlane(h_b, k);
        aia = fmaf(w.x, ha, aia); afa = fmaf(w.y, ha, afa);
        aga = fmaf(w.z, ha, aga); aoa = fmaf(w.w, ha, aoa);
        aib = fmaf(w.x, hb, aib); afb = fmaf(w.y, hb, afb);
        agb = fmaf(w.z, hb, agb); aob = fmaf(w.w, hb, aob);
      }
      c_a = sigm(afa) * c_a + sigm(aia) * tanhf_(aga);
      h_a = sigm(aoa) * tanhf_(c_a);
      c_b = sigm(afb) * c_b + sigm(aib) * tanhf_(agb);
      h_b = sigm(aob) * tanhf_(c_b);
    }
  }

  // ---- heads (per-batch; tiny) ----
#pragma unroll 1
  for (int sel = 0; sel < 2; ++sel) {
    int b = b0 + sel;
    float hh = sel ? h_b : h_a, cc = sel ? c_b : c_a;

    float muv = 0.f, lvv = 0.f;
#pragma unroll 1
    for (int l = 0; l < 16; ++l) {
      float pm = hh * p.W_mu[l * 128 + lane] + cc * p.W_mu[l * 128 + 64 + lane];
      float sm = wsum(pm);
      float pl = hh * p.W_lv[l * 128 + lane] + cc * p.W_lv[l * 128 + 64 + lane];
      float sl = wsum(pl);
      if (lane == l) { muv = sm + p.b_mu[l]; lvv = sl + p.b_lv[l]; }
    }
    if (lane < 16) {
      p.out_mu[b * L_ + lane] = muv;
      p.out_lv[b * L_ + lane] = lvv;
    }
    float mub[16];
#pragma unroll
    for (int l = 0; l < 16; ++l) mub[l] = __shfl(muv, l, 64);

    // decoder init h0/c0
    float s0 = p.b_l2h[lane], s1 = p.b_l2h2[lane];
#pragma unroll
    for (int l = 0; l < 16; ++l) {
      s0 = fmaf(mub[l], p.W_l2h[lane * 16 + l], s0);
      s1 = fmaf(mub[l], p.W_l2h2[lane * 16 + l], s1);
    }
    p.ws_h0[b * H_ + lane] = lrelu(s0);
    p.ws_c0[b * H_ + lane] = lrelu(s1);

    // num head
    float sn = p.b_seq[lane];
#pragma unroll
    for (int l = 0; l < 16; ++l) sn = fmaf(mub[l], p.W_seq[lane * 16 + l], sn);
    sn = lrelu(sn);
    float rn = wsum(sn * p.W_seq2[lane]) + p.b_seq2[0];
    if (lane == 0) p.out_num[b] = fmaxf(rn, 0.f);

    // mass head
    float m1 = p.b_m1[lane];
#pragma unroll
    for (int l = 0; l < 16; ++l) m1 = fmaf(mub[l], p.W_m1[lane * 16 + l], m1);
    m1 = lrelu(m1);
    float m2 = p.b_m2[lane];
#pragma unroll
    for (int k = 0; k < 64; ++k) m2 = fmaf(rdlane(m1, k), p.W_m2[lane * 64 + k], m2);
    m2 = lrelu(m2);
    float r0 = wsum(m2 * p.W_m3[lane]) + p.b_m3[0];
    float r1 = wsum(m2 * p.W_m3[64 + lane]) + p.b_m3[1];
    if (lane == 0) {
      float mx = fmaxf(r0, r1);
      float e0 = __expf(r0 - mx), e1 = __expf(r1 - mx);
      float inv = 1.0f / (e0 + e1);
      p.out_mass[b * P_ + 0] = e0 * inv;
      p.out_mass[b * P_ + 1] = e1 * inv;
    }
  }
}

// ---------------- decoder: 512-step autoregressive LSTM + output proj ----------------
struct DecP {
  const float* ws; const float* b_out;
  float* out_recon;
};

__global__ __launch_bounds__(256) void dec_kernel(DecP p) {
  __shared__ float sA[2 * 64 * 64 * 4];   // ih [k][j][g] then hh [k][j][g]
  __shared__ float sWout[512];            // [i][d][c]
  int tid = threadIdx.x;
  {
    const float4* s = (const float4*)(p.ws + OFF_AD);
    float4* d = (float4*)sA;
    for (int i = tid; i < 8192; i += 256) d[i] = s[i];
    for (int i = tid; i < 512; i += 256) sWout[i] = p.ws[OFF_WOUT + i];
  }
  __syncthreads();

  int wave = tid >> 6, lane = tid & 63;
  int b0 = blockIdx.x * 8 + wave * 2, b1 = b0 + 1;

  float bd0 = p.ws[OFF_BD + lane],       bd1 = p.ws[OFF_BD + 64 + lane],
        bd2 = p.ws[OFF_BD + 128 + lane], bd3 = p.ws[OFF_BD + 192 + lane];

  float hs_a = p.ws[OFF_H0 + b0 * H_ + lane], hs_b = p.ws[OFF_H0 + b1 * H_ + lane];
  float cs_a = p.ws[OFF_C0 + b0 * H_ + lane], cs_b = p.ws[OFF_C0 + b1 * H_ + lane];
  float rx_a = fmaxf(p.ws[OFF_INP0 + lane], 0.f);   // x_0 = relu(inp0)
  float rx_b = rx_a;

  int dd = lane & 7, cg = lane >> 3;
  float bod = p.b_out[dd];
  float* oa = p.out_recon + (size_t)b0 * T_ * D_;
  float* ob = p.out_recon + (size_t)b1 * T_ * D_;

  for (int t = 0; t < T_; ++t) {
    float aia = bd0, afa = bd1, aga = bd2, aoa = bd3;
    float aib = bd0, afb = bd1, agb = bd2, aob = bd3;
#pragma unroll
    for (int k = 0; k < 64; ++k) {
      float4 wi = *(const float4*)&sA[(k * 64 + lane) * 4];
      float4 wh = *(const float4*)&sA[16384 + (k * 64 + lane) * 4];
      float xa = rdlane(rx_a, k), ha = rdlane(hs_a, k);
      float xb = rdlane(rx_b, k), hb = rdlane(hs_b, k);
      aia = fmaf(wi.x, xa, aia); aia = fmaf(wh.x, ha, aia);
      afa = fmaf(wi.y, xa, afa); afa = fmaf(wh.y, ha, afa);
      aga = fmaf(wi.z, xa, aga); aga = fmaf(wh.z, ha, aga);
      aoa = fmaf(wi.w, xa, aoa); aoa = fmaf(wh.w, ha, aoa);
      aib = fmaf(wi.x, xb, aib); aib = fmaf(wh.x, hb, aib);
      afb = fmaf(wi.y, xb, afb); afb = fmaf(wh.y, hb, afb);
      agb = fmaf(wi.z, xb, agb); agb = fmaf(wh.z, hb, agb);
      aob = fmaf(wi.w, xb, aob); aob = fmaf(wh.w, hb, aob);
    }
    cs_a = sigm(afa) * cs_a + sigm(aia) * tanhf_(aga);
    float hn_a = sigm(aoa) * tanhf_(cs_a);
    cs_b = sigm(afb) * cs_b + sigm(aib) * tanhf_(agb);
    float hn_b = sigm(aob) * tanhf_(cs_b);

    // y = h_new @ W_out^T + b_out  (lane j: d = j&7, chunk cg = j>>3)
    float ya = 0.f, yb = 0.f;
#pragma unroll
    for (int i = 0; i < 8; ++i) {
      float w = sWout[i * 64 + dd * 8 + cg];
      ya = fmaf(w, __shfl(hn_a, cg * 8 + i, 64), ya);
      yb = fmaf(w, __shfl(hn_b, cg * 8 + i, 64), yb);
    }
    ya += __shfl_xor(ya, 8, 64); ya += __shfl_xor(ya, 16, 64); ya += __shfl_xor(ya, 32, 64);
    yb += __shfl_xor(yb, 8, 64); yb += __shfl_xor(yb, 16, 64); yb += __shfl_xor(yb, 32, 64);
    if (lane < 8) {
      oa[t * 8 + lane] = ya + bod;
      ob[t * 8 + lane] = yb + bod;
    }
    hs_a = hn_a; hs_b = hn_b;
    rx_a = fmaxf(hn_a, 0.f); rx_b = fmaxf(hn_b, 0.f);
  }
}

// ---------------- host ----------------
extern "C" void kernel_launch(void* const* d_in, const int* in_sizes, int n_in,
                              void* d_out, int out_size, void* d_ws, size_t ws_size,
                              hipStream_t stream) {
  const float* x       = (const float*)d_in[0];
  const float* start   = (const float*)d_in[1];
  const float* W_ih_e  = (const float*)d_in[2];
  const float* W_hh_e  = (const float*)d_in[3];
  const float* b_ih_e  = (const float*)d_in[4];
  const float* b_hh_e  = (const float*)d_in[5];
  const float* W_mu    = (const float*)d_in[6];
  const float* b_mu    = (const float*)d_in[7];
  const float* W_lv    = (const float*)d_in[8];
  const float* b_lv    = (const float*)d_in[9];
  const float* W_l2h   = (const float*)d_in[10];
  const float* b_l2h   = (const float*)d_in[11];
  const float* W_l2h2  = (const float*)d_in[12];
  const float* b_l2h2  = (const float*)d_in[13];
  const float* W_emb   = (const float*)d_in[14];
  const float* b_emb   = (const float*)d_in[15];
  const float* W_ih_d  = (const float*)d_in[16];
  const float* W_hh_d  = (const float*)d_in[17];
  const float* b_ih_d  = (const float*)d_in[18];
  const float* b_hh_d  = (const float*)d_in[19];
  const float* W_out   = (const float*)d_in[20];
  const float* b_out   = (const float*)d_in[21];
  const float* W_seq   = (const float*)d_in[22];
  const float* b_seq   = (const float*)d_in[23];
  const float* W_seq2  = (const float*)d_in[24];
  const float* b_seq2  = (const float*)d_in[25];
  const float* W_m1    = (const float*)d_in[26];
  const float* b_m1    = (const float*)d_in[27];
  const float* W_m2    = (const float*)d_in[28];
  const float* b_m2    = (const float*)d_in[29];
  const float* W_m3    = (const float*)d_in[30];
  const float* b_m3    = (const float*)d_in[31];

  float* ws  = (float*)d_ws;
  float* out = (float*)d_out;
  float* out_mu   = out + (size_t)B_ * T_ * D_;
  float* out_lv   = out_mu + B_ * L_;
  float* out_num  = out_lv + B_ * L_;
  float* out_mass = out_num + B_;

  PrepP pp{W_ih_e, W_hh_e, b_ih_e, b_hh_e, W_ih_d, W_hh_d, b_ih_d, b_hh_d,
           W_out, start, W_emb, b_emb, ws};
  hipLaunchKernelGGL(prep_kernel, dim3(205), dim3(256), 0, stream, pp);

  EncP ep{x, ws, W_mu, b_mu, W_lv, b_lv, W_l2h, b_l2h, W_l2h2, b_l2h2,
          W_seq, b_seq, W_seq2, b_seq2, W_m1, b_m1, W_m2, b_m2, W_m3, b_m3,
          out_mu, out_lv, out_num, out_mass, ws + OFF_H0, ws + OFF_C0};
  hipLaunchKernelGGL(enc_kernel, dim3(256), dim3(256), 0, stream, ep);

  DecP dp{ws, b_out, out};
  hipLaunchKernelGGL(dec_kernel, dim3(256), dim3(256), 0, stream, dp);
}